// Round 6
// baseline (269.660 us; speedup 1.0000x reference)
//
#include <hip/hip_runtime.h>
#include <cmath>

#define D 128
#define NCLS 40
#define BCAP 48

typedef __bf16 bfrag __attribute__((ext_vector_type(8)));
typedef __bf16 bf2 __attribute__((ext_vector_type(2)));
typedef float ffrag __attribute__((ext_vector_type(4)));
typedef unsigned int u32;

struct __align__(8) Edge { int s; float w; };

// ---------------- weights -> bf16, transposed [n][k] ----------------
__global__ __launch_bounds__(256) void cvt_weights(const float* __restrict__ W1, const float* __restrict__ W2,
                                                   const float* __restrict__ Wl, __bf16* __restrict__ Wt1,
                                                   __bf16* __restrict__ Wt2, __bf16* __restrict__ Wlt) {
  int i = blockIdx.x * 256 + threadIdx.x;
  if (i < 16384) {
    int n = i >> 7, k = i & 127;
    Wt1[i] = (__bf16)W1[k * D + n];
  } else if (i < 32768) {
    int j = i - 16384;
    int n = j >> 7, k = j & 127;
    Wt2[j] = (__bf16)W2[k * D + n];
  } else if (i < 32768 + 48 * D) {
    int j = i - 32768;
    int n = j >> 7, k = j & 127;
    Wlt[j] = (n < NCLS) ? (__bf16)Wl[k * NCLS + n] : (__bf16)0.0f;
  }
}

// ---------------- single-pass adjacency buckets (Edge slots, w patched later) ----------------
__global__ __launch_bounds__(256) void fill_ebuckets(const int* __restrict__ src, const int* __restrict__ dst,
                                                     int* __restrict__ count, Edge* __restrict__ eb, int E) {
  int e = blockIdx.x * 256 + threadIdx.x;
  if (e < E) {
    int s = src[e], d = dst[e];
    int pos = atomicAdd(&count[d], 1);
    if (pos < BCAP) {  // Poisson(12): P(deg>48) ~ 2e-10 -- clamp for safety
      Edge ed; ed.s = s; ed.w = 0.0f;
      eb[(size_t)d * BCAP + pos] = ed;
    }
  }
}

// patch w = dinv[s]*dinv[d] in place; wave per node, lane = slot
__global__ __launch_bounds__(256) void weight_buckets(const int* __restrict__ count, Edge* __restrict__ eb, int N) {
  int node = blockIdx.x * 4 + (threadIdx.x >> 6);
  if (node >= N) return;
  int lane = threadIdx.x & 63;
  int cd = count[node];
  float dv = rsqrtf((float)cd + 1.0f);
  int cnt = cd > BCAP ? BCAP : cd;
  if (lane < cnt) {
    Edge ed = eb[(size_t)node * BCAP + lane];
    ed.w = dv * rsqrtf((float)count[ed.s] + 1.0f);
    eb[(size_t)node * BCAP + lane] = ed;
  }
}

// ---------------- fused propagate (bf16 in/out, fp32 accumulate) ----------------
__global__ __launch_bounds__(256) void gather_bf16(const __bf16* __restrict__ t, const int* __restrict__ count,
                                                   const Edge* __restrict__ eb, const float* __restrict__ bias,
                                                   __bf16* __restrict__ out, int N) {
  int node = blockIdx.x * 4 + (threadIdx.x >> 6);
  if (node >= N) return;
  int lane = threadIdx.x & 63;
  int cd = __builtin_amdgcn_readfirstlane(count[node]);
  float dv = rsqrtf((float)cd + 1.0f);
  int cnt = cd > BCAP ? BCAP : cd;
  const Edge* bk = eb + (size_t)node * BCAP;
  bf2 tv = *(const bf2*)(t + (size_t)node * D + lane * 2);
  float ax = dv * dv * (float)tv[0];
  float ay = dv * dv * (float)tv[1];
  int j = 0;
  for (; j + 4 <= cnt; j += 4) {
    Edge e0 = bk[j], e1 = bk[j + 1], e2 = bk[j + 2], e3 = bk[j + 3];
    bf2 r0 = *(const bf2*)(t + (size_t)e0.s * D + lane * 2);
    bf2 r1 = *(const bf2*)(t + (size_t)e1.s * D + lane * 2);
    bf2 r2 = *(const bf2*)(t + (size_t)e2.s * D + lane * 2);
    bf2 r3 = *(const bf2*)(t + (size_t)e3.s * D + lane * 2);
    ax += e0.w * (float)r0[0]; ay += e0.w * (float)r0[1];
    ax += e1.w * (float)r1[0]; ay += e1.w * (float)r1[1];
    ax += e2.w * (float)r2[0]; ay += e2.w * (float)r2[1];
    ax += e3.w * (float)r3[0]; ay += e3.w * (float)r3[1];
  }
  for (; j < cnt; ++j) {
    Edge ed = bk[j];
    bf2 r = *(const bf2*)(t + (size_t)ed.s * D + lane * 2);
    ax += ed.w * (float)r[0]; ay += ed.w * (float)r[1];
  }
  float2 bv = *(const float2*)(bias + lane * 2);
  bf2 o;
  o[0] = (__bf16)tanhf(ax + bv.x);
  o[1] = (__bf16)tanhf(ay + bv.y);
  __builtin_nontemporal_store(*(u32*)&o, (u32*)(out + (size_t)node * D + lane * 2));
}

// ---------------- gather2 + head, wave-local (no barrier, broadcast-only LDS reads) ----------------
__global__ __launch_bounds__(256) void gather_head(const __bf16* __restrict__ t, const int* __restrict__ count,
                                                   const Edge* __restrict__ eb, const float* __restrict__ bias,
                                                   const __bf16* __restrict__ Wlt, const float* __restrict__ blin,
                                                   float* __restrict__ out, int N) {
  __shared__ float hs[4][D];
  const int wid = threadIdx.x >> 6;
  const int lane = threadIdx.x & 63;
  int node = blockIdx.x * 4 + wid;
  if (node >= N) return;
  int cd = __builtin_amdgcn_readfirstlane(count[node]);
  float dv = rsqrtf((float)cd + 1.0f);
  int cnt = cd > BCAP ? BCAP : cd;
  const Edge* bk = eb + (size_t)node * BCAP;
  bf2 tv = *(const bf2*)(t + (size_t)node * D + lane * 2);
  float ax = dv * dv * (float)tv[0];
  float ay = dv * dv * (float)tv[1];
  int j = 0;
  for (; j + 4 <= cnt; j += 4) {
    Edge e0 = bk[j], e1 = bk[j + 1], e2 = bk[j + 2], e3 = bk[j + 3];
    bf2 r0 = *(const bf2*)(t + (size_t)e0.s * D + lane * 2);
    bf2 r1 = *(const bf2*)(t + (size_t)e1.s * D + lane * 2);
    bf2 r2 = *(const bf2*)(t + (size_t)e2.s * D + lane * 2);
    bf2 r3 = *(const bf2*)(t + (size_t)e3.s * D + lane * 2);
    ax += e0.w * (float)r0[0]; ay += e0.w * (float)r0[1];
    ax += e1.w * (float)r1[0]; ay += e1.w * (float)r1[1];
    ax += e2.w * (float)r2[0]; ay += e2.w * (float)r2[1];
    ax += e3.w * (float)r3[0]; ay += e3.w * (float)r3[1];
  }
  for (; j < cnt; ++j) {
    Edge ed = bk[j];
    bf2 r = *(const bf2*)(t + (size_t)ed.s * D + lane * 2);
    ax += ed.w * (float)r[0]; ay += ed.w * (float)r[1];
  }
  float2 bv = *(const float2*)(bias + lane * 2);
  float2 hv;
  hv.x = tanhf(ax + bv.x);
  hv.y = tanhf(ay + bv.y);
  *(float2*)&hs[wid][lane * 2] = hv;  // intra-wave LDS round-trip; compiler inserts lgkmcnt wait

  // head: lanes 0..39 each compute one class; LDS reads are wave-uniform (broadcast, conflict-free)
  if (lane < NCLS) {
    float acc = blin[lane];
    const __bf16* wp = Wlt + lane * D;
#pragma unroll
    for (int k8 = 0; k8 < D; k8 += 8) {
      bfrag w8 = *(const bfrag*)(wp + k8);
      float4 h0 = *(const float4*)&hs[wid][k8];
      float4 h1 = *(const float4*)&hs[wid][k8 + 4];
      acc += h0.x * (float)w8[0] + h0.y * (float)w8[1] + h0.z * (float)w8[2] + h0.w * (float)w8[3]
           + h1.x * (float)w8[4] + h1.y * (float)w8[5] + h1.z * (float)w8[6] + h1.w * (float)w8[7];
    }
    out[(size_t)node * NCLS + lane] = acc;
  }
}

// ---------------- MFMA GEMM: C[N,128] = A[N,128] @ B[128,128] ----------------
template <typename AT>
__global__ __launch_bounds__(256) void gemm_mfma(const AT* __restrict__ A, const __bf16* __restrict__ Wt,
                                                 __bf16* __restrict__ C, int N) {
  __shared__ __align__(16) __bf16 Bs[128][136];
  const int tid = threadIdx.x;
  const int wave = tid >> 6, lane = tid & 63;
  const int row0 = blockIdx.x * 128 + wave * 32;
  const int koff = (lane >> 4) * 8;

  for (int i = tid; i < 128 * 16; i += 256) {
    int n = i >> 4, seg = i & 15;
    *(uint4*)&Bs[n][seg * 8] = *(const uint4*)(Wt + n * D + seg * 8);
  }

  bfrag a[2][4];
#pragma unroll
  for (int mt = 0; mt < 2; ++mt) {
    int r = row0 + mt * 16 + (lane & 15);
    int rc = r < N ? r : N - 1;
    const AT* p = A + (size_t)rc * D;
#pragma unroll
    for (int kk = 0; kk < 4; ++kk) {
      if constexpr (sizeof(AT) == 4) {
        float4 u = *(const float4*)(p + kk * 32 + koff);
        float4 v = *(const float4*)(p + kk * 32 + koff + 4);
        bfrag f;
        f[0] = (__bf16)u.x; f[1] = (__bf16)u.y; f[2] = (__bf16)u.z; f[3] = (__bf16)u.w;
        f[4] = (__bf16)v.x; f[5] = (__bf16)v.y; f[6] = (__bf16)v.z; f[7] = (__bf16)v.w;
        a[mt][kk] = f;
      } else {
        a[mt][kk] = *(const bfrag*)(p + kk * 32 + koff);
      }
    }
  }
  __syncthreads();

  ffrag acc[2][8];
#pragma unroll
  for (int mt = 0; mt < 2; ++mt)
#pragma unroll
    for (int n = 0; n < 8; ++n) acc[mt][n] = (ffrag){0.f, 0.f, 0.f, 0.f};

#pragma unroll
  for (int kk = 0; kk < 4; ++kk) {
#pragma unroll
    for (int n = 0; n < 8; ++n) {
      bfrag b = *(const bfrag*)(&Bs[n * 16 + (lane & 15)][kk * 32 + koff]);
      acc[0][n] = __builtin_amdgcn_mfma_f32_16x16x32_bf16(a[0][kk], b, acc[0][n], 0, 0, 0);
      acc[1][n] = __builtin_amdgcn_mfma_f32_16x16x32_bf16(a[1][kk], b, acc[1][n], 0, 0, 0);
    }
  }

  int ocol = lane & 15;
#pragma unroll
  for (int mt = 0; mt < 2; ++mt) {
    int orow0 = row0 + mt * 16 + (lane >> 4) * 4;
#pragma unroll
    for (int n = 0; n < 8; ++n)
#pragma unroll
      for (int i = 0; i < 4; ++i) {
        int r = orow0 + i;
        if (r < N) C[(size_t)r * D + n * 16 + ocol] = (__bf16)acc[mt][n][i];
      }
  }
}

extern "C" void kernel_launch(void* const* d_in, const int* in_sizes, int n_in,
                              void* d_out, int out_size, void* d_ws, size_t ws_size,
                              hipStream_t stream) {
  const float* x    = (const float*)d_in[0];
  const int*   ei   = (const int*)d_in[1];
  const float* W1   = (const float*)d_in[2];
  const float* b1   = (const float*)d_in[3];
  const float* W2   = (const float*)d_in[4];
  const float* b2   = (const float*)d_in[5];
  const float* Wlin = (const float*)d_in[6];
  const float* blin = (const float*)d_in[7];
  float* out = (float*)d_out;

  const int N = in_sizes[0] / D;   // 50000
  const int E = in_sizes[1] / 2;   // 600000
  const int* srcp = ei;
  const int* dstp = ei + E;

  // workspace layout (~45 MB)
  char* ws = (char*)d_ws;
  int*    count = (int*)(ws);                        // 200 KB
  __bf16* Wt1   = (__bf16*)(ws + (size_t)262144);    // 32 KB
  __bf16* Wt2   = (__bf16*)(ws + (size_t)294912);    // 32 KB
  __bf16* Wlt   = (__bf16*)(ws + (size_t)327680);    // 12 KB
  Edge*   eb    = (Edge*)(ws + (size_t)1048576);     // 50000*48*8 = 19.2 MB
  __bf16* tb    = (__bf16*)(ws + (size_t)20971520);  // 12.8 MB
  __bf16* hb    = (__bf16*)(ws + (size_t)33771520);  // 12.8 MB

  dim3 b256(256);

  cvt_weights<<<152, b256, 0, stream>>>(W1, W2, Wlin, Wt1, Wt2, Wlt);
  hipMemsetAsync(count, 0, (size_t)N * sizeof(int), stream);
  fill_ebuckets<<<(E + 255) / 256, b256, 0, stream>>>(srcp, dstp, count, eb, E);
  weight_buckets<<<(N + 3) / 4, b256, 0, stream>>>(count, eb, N);

  const int gg = (N + 127) / 128;  // 391

  // layer 1 (A = fp32 x, converted in-register)
  gemm_mfma<float><<<gg, b256, 0, stream>>>(x, Wt1, tb, N);
  gather_bf16<<<(N + 3) / 4, b256, 0, stream>>>(tb, count, eb, b1, hb, N);

  // layer 2
  gemm_mfma<__bf16><<<gg, b256, 0, stream>>>(hb, Wt2, tb, N);

  // layer-2 propagate + head fused
  gather_head<<<(N + 3) / 4, b256, 0, stream>>>(tb, count, eb, b2, Wlt, blin, out, N);
}